// Round 6
// baseline (199.921 us; speedup 1.0000x reference)
//
#include <hip/hip_runtime.h>

#define MIN_V 1e-7f
#define MAX_V 10.0f
#define INV15 (1.0f/15.0f)
#define CAP 32

typedef _Float16 half2v __attribute__((ext_vector_type(2)));
typedef _Float16 half4v __attribute__((ext_vector_type(4)));
typedef _Float16 half8v __attribute__((ext_vector_type(8)));

static __device__ __forceinline__ float clipv(float v){
    return fminf(fmaxf(v, MIN_V), MAX_V);
}

// Pure streaming pass: CH[i] = fp16(clip(H[i])), grid-stride, 8 elems/thread/iter
__global__ __launch_bounds__(256) void ch_stream(const float* __restrict__ H,
                                                 _Float16* __restrict__ CH, int total8){
    int stride = gridDim.x*256;
    for (int i = blockIdx.x*256 + threadIdx.x; i < total8; i += stride){
        const float4* p = (const float4*)(H + (size_t)i*8);
        float4 a = p[0], b = p[1];
        half8v o;
        o[0]=(_Float16)clipv(a.x); o[1]=(_Float16)clipv(a.y);
        o[2]=(_Float16)clipv(a.z); o[3]=(_Float16)clipv(a.w);
        o[4]=(_Float16)clipv(b.x); o[5]=(_Float16)clipv(b.y);
        o[6]=(_Float16)clipv(b.z); o[7]=(_Float16)clipv(b.w);
        *(half8v*)(CH + (size_t)i*8) = o;
    }
}

// node -> edge incidence lists (ushort edge ids; one 64B line per node)
__global__ void build_lists(const int* __restrict__ edges, int* __restrict__ cnt,
                            unsigned short* __restrict__ lists, int total){
    int i = blockIdx.x*256 + threadIdx.x;
    if (i >= total) return;
    int node = edges[i];
    int p = atomicAdd(&cnt[node], 1);
    if (p < CAP) lists[(size_t)node*CAP + p] = (unsigned short)(i >> 4);
}

// ES1s[e][d] = (1/15) * sum_s CH[idx_s][d]^2, fp16.
// Half-wave per edge, lane covers 4 dims (8-B loads, 256-B coalesced rows).
__global__ __launch_bounds__(256) void es_l1(const _Float16* __restrict__ CH,
                                             const int* __restrict__ edges,
                                             _Float16* __restrict__ ES1s, int E){
    int tid = threadIdx.x;
    int hw = tid >> 5, l32 = tid & 31;
    int e = blockIdx.x*8 + hw;
    if (e >= E) return;
    int nid = edges[(size_t)e*16 + (l32 & 15)];   // lane s holds node id s (dup x2)
    int dq = l32 * 4;
    float s0=0.f, s1=0.f, s2=0.f, s3=0.f;
    #pragma unroll
    for (int s=0;s<16;++s){
        int idx = __shfl(nid, s, 32);
        half4v v = *(const half4v*)(CH + (size_t)idx*128 + dq);
        float f0=(float)v[0], f1=(float)v[1], f2=(float)v[2], f3=(float)v[3];
        s0 += f0*f0; s1 += f1*f1; s2 += f2*f2; s3 += f3*f3;
    }
    half4v o;
    o[0]=(_Float16)(s0*INV15); o[1]=(_Float16)(s1*INV15);
    o[2]=(_Float16)(s2*INV15); o[3]=(_Float16)(s3*INV15);
    *(half4v*)(ES1s + (size_t)e*128 + dq) = o;
}

// Fused layer-1: gather (half-wave/node, unroll-2, zero-row padded -> maskless,
// packed-f16 sub/max + v_sqrt_f16, f32 accumulate) -> LDS (f16) -> dot2 gemm.
__global__ __launch_bounds__(256) void fused_l1(
    const _Float16* __restrict__ CH, const _Float16* __restrict__ ES1s,
    const int* __restrict__ cnt, const unsigned short* __restrict__ lists,
    const float* __restrict__ W1, const float* __restrict__ b1,
    _Float16* __restrict__ X, int N, int EZERO){
    __shared__ _Float16 snw[8*128];
    int tid = threadIdx.x;
    int wave = tid >> 6, lane = tid & 63;

    // phase-2 weight preload (f16 pairs): lane (q,h) holds W1[q*32+2i..+1][h]
    int q = lane >> 4, h = lane & 15;
    half2v w2[16];
    #pragma unroll
    for (int i=0;i<16;++i){
        w2[i][0] = (_Float16)W1[(q*32+2*i  )*16 + h];
        w2[i][1] = (_Float16)W1[(q*32+2*i+1)*16 + h];
    }
    const half2v ones = {(_Float16)1.f, (_Float16)1.f};
    float bv = b1[h];

    int hw = tid >> 5;        // half-wave id 0..7
    int k32 = tid & 31;
    int dq = k32 * 4;
    int nb = blockIdx.x * 8;

    // ---- phase 1: gather node nb+hw ----
    int n = nb + hw;
    if (n < N){
        int len = cnt[n]; if (len > CAP) len = CAP;
        int myid = (int)lists[(size_t)n*CAP + k32];
        myid = (k32 < len) ? myid : EZERO;          // pad slots -> zeros row (exact 0 contrib)

        half4v hv = *(const half4v*)(CH + (size_t)n*128 + dq);
        const _Float16 i15 = (_Float16)INV15;
        half4v i15v = {i15, i15, i15, i15};
        half4v p16 = (hv * hv) * i15v;
        const half4v z4 = {(_Float16)0.f,(_Float16)0.f,(_Float16)0.f,(_Float16)0.f};

        float a0=0.f, a1=0.f, a2=0.f, a3=0.f;
        int iters = (len + 1) & ~1;
        for (int k0=0;k0<iters;k0+=2){
            int e0 = __shfl(myid, k0,   32);
            int e1 = __shfl(myid, k0+1, 32);
            half4v v0 = *(const half4v*)(ES1s + (size_t)e0*128 + dq);
            half4v v1 = *(const half4v*)(ES1s + (size_t)e1*128 + dq);
            half4v m0 = __builtin_elementwise_max(v0 - p16, z4);
            half4v m1 = __builtin_elementwise_max(v1 - p16, z4);
            half4v s0 = __builtin_elementwise_sqrt(m0);
            half4v s1 = __builtin_elementwise_sqrt(m1);
            a0 += (float)s0[0] + (float)s1[0];
            a1 += (float)s0[1] + (float)s1[1];
            a2 += (float)s0[2] + (float)s1[2];
            a3 += (float)s0[3] + (float)s1[3];
        }
        half4v o;
        o[0] = (_Float16)((float)hv[0] + a0);
        o[1] = (_Float16)((float)hv[1] + a1);
        o[2] = (_Float16)((float)hv[2] + a2);
        o[3] = (_Float16)((float)hv[3] + a3);
        *(half4v*)&snw[hw*128 + dq] = o;
    }
    __syncthreads();

    // ---- phase 2: wave handles nodes nb+wave*2 .. +1, dot2 gemm ----
    #pragma unroll
    for (int r=0;r<2;++r){
        int nl = wave*2 + r;
        int n2 = nb + nl;
        if (n2 >= N) continue;
        float acc = 0.f, rs = 0.f;
        #pragma unroll
        for (int j=0;j<8;++j){
            half4v v = *(const half4v*)&snw[nl*128 + q*32 + j*4];
            half2v lo = {v[0], v[1]}, hi = {v[2], v[3]};
            acc = __builtin_amdgcn_fdot2(lo, w2[j*2  ], acc, false);
            acc = __builtin_amdgcn_fdot2(hi, w2[j*2+1], acc, false);
            rs  = __builtin_amdgcn_fdot2(lo, ones, rs, false);
            rs  = __builtin_amdgcn_fdot2(hi, ones, rs, false);
        }
        acc += __shfl_xor(acc, 16, 64);
        rs  += __shfl_xor(rs , 16, 64);
        acc += __shfl_xor(acc, 32, 64);
        rs  += __shfl_xor(rs , 32, 64);
        if (q == 0){
            float o = acc * __builtin_amdgcn_rcpf(rs) + bv;
            X[(size_t)n2*16 + h] = (_Float16)fmaxf(o, 0.f);
        }
    }
}

// ES2s[e][d] = (1/15) * sum_s clipfloor(X[idx_s][d])^2, fp16. Thread = (edge, 4 dims).
// (X <= 0.5 provably, so the upper clip at 10 is a no-op; only the 1e-7 floor matters.)
__global__ __launch_bounds__(256) void es_l2(const _Float16* __restrict__ X,
                                             const int* __restrict__ edges,
                                             _Float16* __restrict__ ES2s, int E){
    int t = blockIdx.x*256 + threadIdx.x;
    int e = t >> 2, dq = (t & 3)*4;
    if (e >= E) return;
    const int* row = edges + (size_t)e*16;
    const _Float16 c7 = (_Float16)1e-7f;
    const half4v c7v = {c7, c7, c7, c7};
    float s0=0.f, s1=0.f, s2=0.f, s3=0.f;
    #pragma unroll
    for (int s=0;s<16;++s){
        half4v v = *(const half4v*)(X + (size_t)row[s]*16 + dq);
        v = __builtin_elementwise_max(v, c7v);
        float f0=(float)v[0], f1=(float)v[1], f2=(float)v[2], f3=(float)v[3];
        s0 += f0*f0; s1 += f1*f1; s2 += f2*f2; s3 += f3*f3;
    }
    half4v o;
    o[0]=(_Float16)(s0*INV15); o[1]=(_Float16)(s1*INV15);
    o[2]=(_Float16)(s2*INV15); o[3]=(_Float16)(s3*INV15);
    *(half4v*)(ES2s + (size_t)e*16 + dq) = o;
}

// Layer-2 fused node update: thread-per-node, zero-row padded, packed-f16 core,
// dot2 gemm with f16 W2 pairs in LDS.
__global__ __launch_bounds__(256) void node_l2(
    const _Float16* __restrict__ X, const _Float16* __restrict__ ES2s,
    const int* __restrict__ cnt, const unsigned short* __restrict__ lists,
    const float* __restrict__ W2, const float* __restrict__ b2,
    float* __restrict__ out, int N, int EZERO){
    __shared__ half2v sW2h[8*40];
    __shared__ float sb[40];
    for (int i=threadIdx.x;i<320;i+=256){
        int d2 = i/40, c = i - d2*40;
        half2v wp;
        wp[0] = (_Float16)W2[(2*d2  )*40 + c];
        wp[1] = (_Float16)W2[(2*d2+1)*40 + c];
        sW2h[i] = wp;
    }
    if (threadIdx.x < 40) sb[threadIdx.x] = b2[threadIdx.x];
    __syncthreads();
    int n = blockIdx.x*256 + threadIdx.x;
    if (n >= N) return;

    const _Float16 c7 = (_Float16)1e-7f;
    const half8v c7v = {c7,c7,c7,c7,c7,c7,c7,c7};
    const half8v z8 = {(_Float16)0.f,(_Float16)0.f,(_Float16)0.f,(_Float16)0.f,
                       (_Float16)0.f,(_Float16)0.f,(_Float16)0.f,(_Float16)0.f};
    const _Float16 i15 = (_Float16)INV15;
    const half8v i15v = {i15,i15,i15,i15,i15,i15,i15,i15};

    const half8v* xr = (const half8v*)(X + (size_t)n*16);
    half8v x0 = __builtin_elementwise_max(xr[0], c7v);
    half8v x1 = __builtin_elementwise_max(xr[1], c7v);
    half8v ps0 = (x0*x0)*i15v;
    half8v ps1 = (x1*x1)*i15v;

    float xc[16], ad[16];
    #pragma unroll
    for (int d=0;d<8;++d){ xc[d]=(float)x0[d]; xc[8+d]=(float)x1[d]; ad[d]=0.f; ad[8+d]=0.f; }

    int len = cnt[n]; if (len > CAP) len = CAP;
    const unsigned short* lrow = lists + (size_t)n*CAP;
    for (int k0=0;k0<len;k0+=2){
        int e0 = lrow[k0];
        int e1 = (k0+1 < len) ? (int)lrow[k0+1] : EZERO;   // zeros row -> exact 0 contrib
        const half8v* r0 = (const half8v*)(ES2s + (size_t)e0*16);
        const half8v* r1 = (const half8v*)(ES2s + (size_t)e1*16);
        half8v sa0 = __builtin_elementwise_sqrt(__builtin_elementwise_max(r0[0]-ps0, z8));
        half8v sb0 = __builtin_elementwise_sqrt(__builtin_elementwise_max(r0[1]-ps1, z8));
        half8v sa1 = __builtin_elementwise_sqrt(__builtin_elementwise_max(r1[0]-ps0, z8));
        half8v sb1 = __builtin_elementwise_sqrt(__builtin_elementwise_max(r1[1]-ps1, z8));
        #pragma unroll
        for (int d=0;d<8;++d){
            ad[d]   += (float)sa0[d] + (float)sa1[d];
            ad[8+d] += (float)sb0[d] + (float)sb1[d];
        }
    }
    float rs = 0.f;
    float nw[16];
    #pragma unroll
    for (int d=0;d<16;++d){ nw[d] = xc[d] + ad[d]; rs += nw[d]; }
    float rinv = __builtin_amdgcn_rcpf(rs);

    half2v nwh[8];
    #pragma unroll
    for (int i=0;i<8;++i){ nwh[i][0] = (_Float16)nw[2*i]; nwh[i][1] = (_Float16)nw[2*i+1]; }

    float4 ob[10];
    #pragma unroll
    for (int c=0;c<40;++c){
        float acc = 0.f;
        #pragma unroll
        for (int d2=0;d2<8;++d2)
            acc = __builtin_amdgcn_fdot2(nwh[d2], sW2h[d2*40+c], acc, false);
        ((float*)ob)[c] = rinv*acc + sb[c];
    }
    float4* op = (float4*)(out + (size_t)n*40);
    #pragma unroll
    for (int j=0;j<10;++j) op[j] = ob[j];
}

extern "C" void kernel_launch(void* const* d_in, const int* in_sizes, int n_in,
                              void* d_out, int out_size, void* d_ws, size_t ws_size,
                              hipStream_t stream){
    (void)n_in; (void)out_size; (void)ws_size;
    const float* H  = (const float*)d_in[0];
    const float* W1 = (const float*)d_in[1];
    const float* b1 = (const float*)d_in[2];
    const float* W2 = (const float*)d_in[3];
    const float* b2 = (const float*)d_in[4];
    const int* edges = (const int*)d_in[5];
    float* out = (float*)d_out;

    const int N = in_sizes[0] / 128;   // 200000
    const int E = in_sizes[5] / 16;    // 40000
    const int total = E * 16;          // 640000
    const int total8 = N * 128 / 8;    // 3.2M

    char* ws = (char*)d_ws;
    size_t off = 0;
    // region A: CH (dead after fused_l1) -> reused for ES2s
    _Float16* CH   = (_Float16*)(ws + off);
    _Float16* ES2s = (_Float16*)(ws + off);                 // (E+1) rows x 32 B = 1.28 MB
    off += (size_t)N*128*sizeof(_Float16);                  // 51.20 MB
    _Float16* ES1s = (_Float16*)(ws + off); off += (size_t)(E+1)*128*sizeof(_Float16); // 10.24 MB
    _Float16* X    = (_Float16*)(ws + off); off += (size_t)N*16*sizeof(_Float16);      //  6.40 MB
    int* cnt = (int*)(ws + off); off += (size_t)N*sizeof(int);                         //  0.80 MB
    unsigned short* lists = (unsigned short*)(ws + off);
    off += (size_t)N*CAP*sizeof(unsigned short);                                       // 12.80 MB

    hipMemsetAsync(cnt, 0, (size_t)N*sizeof(int), stream);
    hipMemsetAsync(ES1s + (size_t)E*128, 0, 128*sizeof(_Float16), stream);  // zeros row
    ch_stream<<<2048, 256, 0, stream>>>(H, CH, total8);
    build_lists<<<(total+255)/256, 256, 0, stream>>>(edges, cnt, lists, total);
    es_l1<<<(E+7)/8, 256, 0, stream>>>(CH, edges, ES1s, E);
    fused_l1<<<(N+7)/8, 256, 0, stream>>>(CH, ES1s, cnt, lists, W1, b1, X, N, E);
    // CH dead from here; ES2s may now overwrite region A
    hipMemsetAsync(ES2s + (size_t)E*16, 0, 16*sizeof(_Float16), stream);    // zeros row
    es_l2<<<(E*4+255)/256, 256, 0, stream>>>(X, edges, ES2s, E);
    node_l2<<<(N+255)/256, 256, 0, stream>>>(X, ES2s, cnt, lists, W2, b2, out, N, E);
}